// Round 1
// baseline (493.101 us; speedup 1.0000x reference)
//
#include <hip/hip_runtime.h>

#define N_ENTITIES 500000
#define N_RELS 1000
#define EMB_DIM 128
#define N_TRIPLES 1000000

// winner[v] = max triple index e with h_idx[e]==v, else -1.
// Last-write-wins (numpy index_put semantics) == max-e-wins.

__global__ void init_winner_kernel(int* __restrict__ winner) {
    int i = blockIdx.x * blockDim.x + threadIdx.x;
    if (i < N_ENTITIES) winner[i] = -1;
}

__global__ void find_winner_kernel(const int* __restrict__ h_idx,
                                   int* __restrict__ winner) {
    int e = blockIdx.x * blockDim.x + threadIdx.x;
    if (e < N_TRIPLES) {
        atomicMax(&winner[h_idx[e]], e);  // deterministic: max is order-independent
    }
}

// One row = 128 floats = 32 lanes x float4 (512 B coalesced per row).
// Block 256 threads -> 8 rows/block.
__global__ void apply_kernel(const float* __restrict__ memory,
                             const float* __restrict__ rel_table,
                             const int* __restrict__ r_idx,
                             const int* __restrict__ t_idx,
                             const int* __restrict__ winner,
                             float* __restrict__ out) {
    int tid  = blockIdx.x * blockDim.x + threadIdx.x;
    int row  = tid >> 5;
    int lane = tid & 31;
    if (row >= N_ENTITIES) return;

    const float4* mrow = (const float4*)(memory + (size_t)row * EMB_DIM);
    float4 h = mrow[lane];

    int w = winner[row];  // broadcast across the 32-lane row group
    float4 val;
    if (w >= 0) {
        int r = r_idx[w];
        int t = t_idx[w];
        float4 rv = ((const float4*)(rel_table + (size_t)r * EMB_DIM))[lane];
        float4 tv = ((const float4*)(memory   + (size_t)t * EMB_DIM))[lane];
        // Match reference rounding exactly: 0.9*h + 0.1*(h + r - t)
        val.x = 0.9f * h.x + 0.1f * (h.x + rv.x - tv.x);
        val.y = 0.9f * h.y + 0.1f * (h.y + rv.y - tv.y);
        val.z = 0.9f * h.z + 0.1f * (h.z + rv.z - tv.z);
        val.w = 0.9f * h.w + 0.1f * (h.w + rv.w - tv.w);
    } else {
        val = h;
    }
    ((float4*)(out + (size_t)row * EMB_DIM))[lane] = val;
}

extern "C" void kernel_launch(void* const* d_in, const int* in_sizes, int n_in,
                              void* d_out, int out_size, void* d_ws, size_t ws_size,
                              hipStream_t stream) {
    const float* memory    = (const float*)d_in[0];
    const float* rel_table = (const float*)d_in[1];
    const int*   h_idx     = (const int*)d_in[2];
    const int*   r_idx     = (const int*)d_in[3];
    const int*   t_idx     = (const int*)d_in[4];
    float*       out       = (float*)d_out;

    int* winner = (int*)d_ws;  // N_ENTITIES ints = 2 MB

    {
        int threads = 256;
        int blocks = (N_ENTITIES + threads - 1) / threads;
        init_winner_kernel<<<blocks, threads, 0, stream>>>(winner);
    }
    {
        int threads = 256;
        int blocks = (N_TRIPLES + threads - 1) / threads;
        find_winner_kernel<<<blocks, threads, 0, stream>>>(h_idx, winner);
    }
    {
        int threads = 256;
        long long total = (long long)N_ENTITIES * 32;
        int blocks = (int)((total + threads - 1) / threads);
        apply_kernel<<<blocks, threads, 0, stream>>>(memory, rel_table, r_idx,
                                                     t_idx, winner, out);
    }
}

// Round 3
// 487.892 us; speedup vs baseline: 1.0107x; 1.0107x over previous
//
#include <hip/hip_runtime.h>

#define N_ENTITIES 500000
#define N_RELS 1000
#define EMB_DIM 128
#define N_TRIPLES 1000000

typedef float floatx4 __attribute__((ext_vector_type(4)));

// winner[v] = max triple index e with h_idx[e]==v, else -1.
// Last-write-wins (numpy index_put semantics) == max-e-wins (order-independent,
// so deterministic under graph replay).

__global__ void init_winner_kernel(int* __restrict__ winner) {
    int i = blockIdx.x * blockDim.x + threadIdx.x;
    if (i < N_ENTITIES) winner[i] = -1;
}

__global__ void find_winner_kernel(const int* __restrict__ h_idx,
                                   int* __restrict__ winner) {
    int e = blockIdx.x * blockDim.x + threadIdx.x;
    if (e < N_TRIPLES) {
        atomicMax(&winner[h_idx[e]], e);
    }
}

// One row = 128 floats = 32 lanes x float4 (512 B coalesced per row).
// memory (244 MB) streams through and fits the 256 MB L3; out-stores are
// nontemporal so they don't evict it -> random t-row gathers can hit L3.
__global__ void apply_kernel(const float* __restrict__ memory,
                             const float* __restrict__ rel_table,
                             const int* __restrict__ r_idx,
                             const int* __restrict__ t_idx,
                             const int* __restrict__ winner,
                             float* __restrict__ out) {
    int tid  = blockIdx.x * blockDim.x + threadIdx.x;
    int row  = tid >> 5;
    int lane = tid & 31;
    if (row >= N_ENTITIES) return;

    // Start the dependent index chain first so its latency overlaps the h load.
    int w = winner[row];

    const floatx4* mrow = (const floatx4*)(memory + (size_t)row * EMB_DIM);
    floatx4 h = mrow[lane];

    floatx4 val = h;
    if (w >= 0) {
        int r = r_idx[w];
        int t = t_idx[w];
        floatx4 rv = ((const floatx4*)(rel_table + (size_t)r * EMB_DIM))[lane];
        floatx4 tv = ((const floatx4*)(memory   + (size_t)t * EMB_DIM))[lane];
        val = 0.9f * h + 0.1f * (h + rv - tv);
    }
    floatx4* orow = (floatx4*)(out + (size_t)row * EMB_DIM) + lane;
    __builtin_nontemporal_store(val, orow);
}

extern "C" void kernel_launch(void* const* d_in, const int* in_sizes, int n_in,
                              void* d_out, int out_size, void* d_ws, size_t ws_size,
                              hipStream_t stream) {
    const float* memory    = (const float*)d_in[0];
    const float* rel_table = (const float*)d_in[1];
    const int*   h_idx     = (const int*)d_in[2];
    const int*   r_idx     = (const int*)d_in[3];
    const int*   t_idx     = (const int*)d_in[4];
    float*       out       = (float*)d_out;

    int* winner = (int*)d_ws;  // N_ENTITIES ints = 2 MB

    {
        int threads = 256;
        int blocks = (N_ENTITIES + threads - 1) / threads;
        init_winner_kernel<<<blocks, threads, 0, stream>>>(winner);
    }
    {
        int threads = 256;
        int blocks = (N_TRIPLES + threads - 1) / threads;
        find_winner_kernel<<<blocks, threads, 0, stream>>>(h_idx, winner);
    }
    {
        int threads = 256;
        long long total = (long long)N_ENTITIES * 32;
        int blocks = (int)((total + threads - 1) / threads);
        apply_kernel<<<blocks, threads, 0, stream>>>(memory, rel_table, r_idx,
                                                     t_idx, winner, out);
    }
}